// Round 4
// baseline (62.141 us; speedup 1.0000x reference)
//
#include <hip/hip_runtime.h>
#include <stdint.h>

typedef _Float16 half_t;
typedef _Float16 v4h __attribute__((ext_vector_type(4)));
typedef float v4f __attribute__((ext_vector_type(4)));

#define HH 256
#define WW 256
#define HW (HH*WW)
#define CF 32
#define TH 8
#define TW 64
#define NROWS (TH+12)     // 20
#define NPX   (TW+16)     // 80
#define NTHREADS 1024
#define L2E 1.44269504088896340736f

__global__ __launch_bounds__(NTHREADS)
void corr_recon(const float* __restrict__ ft, const float* __restrict__ fr,
                const float* __restrict__ img, float* __restrict__ out)
{
    // [row 20][px 80][c 32] f16, c in 4-channel granules XOR-swizzled by (px&7)
    __shared__ half_t frl[NROWS * NPX * CF];   // 102400 B

    const int bid = blockIdx.x;
    const int b0  = bid >> 7;
    const int rb  = bid & 127;
    const int y0  = (rb >> 2) * TH;    // 32 row-bands
    const int x0t = (rb & 3) * TW;     // 4 col-bands

    const int tid  = threadIdx.x;
    const int lane = tid & 63;
    const int w    = tid >> 6;         // wave 0..15
    const int n    = lane & 15;        // MFMA col (key px within tile)
    const int g    = lane >> 4;        // MFMA row group

    const float* frb = fr  + (size_t)b0 * CF * HW;
    const float* ftb = ft  + (size_t)b0 * CF * HW;
    const float* imb = img + (size_t)b0 * HW;

    // ---- stage fr tile: f32 global -> f16 LDS, swizzled granules ----
    for (int i = tid; i < NROWS * 20 * 8; i += NTHREADS) {
        const int px4 = i % 20;        // 4-px group
        const int t2  = i / 20;
        const int q   = t2 & 7;        // 4-channel granule (c = 4q..4q+3)
        const int row = t2 >> 3;
        const int gy  = y0 - 6 + row;
        const int gx  = x0t - 6 + px4 * 4;
        const int gyc = min(max(gy, 0), HH-1);
        const bool oky = (gy == gyc);
        const float* src = frb + ((size_t)(4*q) * HH + gyc) * WW;
        float t[4][4];
        if (oky && gx >= 0 && gx + 3 < WW) {
            #pragma unroll
            for (int jc = 0; jc < 4; ++jc) {
                float4 v = *(const float4*)(src + (size_t)jc * HW + gx);
                t[jc][0]=v.x; t[jc][1]=v.y; t[jc][2]=v.z; t[jc][3]=v.w;
            }
        } else {
            #pragma unroll
            for (int jc = 0; jc < 4; ++jc)
                #pragma unroll
                for (int e = 0; e < 4; ++e) {
                    int x = gx + e;
                    t[jc][e] = (oky && x >= 0 && x < WW) ? src[(size_t)jc * HW + x] : 0.f;
                }
        }
        #pragma unroll
        for (int jp = 0; jp < 4; ++jp) {
            const int px = px4 * 4 + jp;
            v4h pk;
            pk[0] = (half_t)t[0][jp]; pk[1] = (half_t)t[1][jp];
            pk[2] = (half_t)t[2][jp]; pk[3] = (half_t)t[3][jp];
            *(v4h*)&frl[(row * NPX + px) * CF + ((q ^ (px & 7)) * 4)] = pk;
        }
    }

    __syncthreads();

    // ---- per-lane band-mask biases (log2-domain; exp2(-1e4) == 0) ----
    v4f bias0, bias1;
    #pragma unroll
    for (int r = 0; r < 4; ++r) {
        const int m  = 4*g + r;
        const int d0 = n - m;           // ktile0 displacement index
        const int d1 = 16 + n - m;      // ktile1 displacement index
        bias0[r] = (d0 >= 0 && d0 <= 12) ? 0.f : -1e4f;
        bias1[r] = (d1 >= 0 && d1 <= 12) ? 0.f : -1e4f;
    }
    const int sw     = n & 7;
    const int off_lo = ((g       ^ sw) * 4);   // c = 4g..4g+3
    const int off_hi = (((4 + g) ^ sw) * 4);   // c = 16+4g..16+4g+3

    // ---- 2 jobs per wave: jj = 2w, 2w+1 ----
    #pragma unroll
    for (int jj2 = 0; jj2 < 2; ++jj2) {
        const int jj = 2*w + jj2;
        const int r8 = jj >> 2;            // q-row in tile (0..7)
        const int xo = (jj & 3) * 16;      // q-x subtile offset
        const int y  = y0 + r8;
        const int x0 = x0t + xo;

        // A fragments: ft[c][y][x0+n], pre-scaled by log2(e)
        const float* fa = ftb + (size_t)y * WW + (x0 + n);
        v4h alo, ahi;
        #pragma unroll
        for (int j = 0; j < 4; ++j) {
            alo[j] = (half_t)(fa[(size_t)(4*g + j)      * HW] * L2E);
            ahi[j] = (half_t)(fa[(size_t)(16 + 4*g + j) * HW] * L2E);
        }

        const int px0  = xo + n;           // ktile0 key px in LDS coords
        const int px1  = px0 + 16;         // ktile1
        const int kx0  = x0 - 6 + n;       // global key x, ktile0
        const int kx1  = kx0 + 16;
        const int kx0c = min(max(kx0, 0), WW-1);
        const int kx1c = min(kx1, WW-1);
        const bool okx0 = (kx0 >= 0) && (kx0 < WW);
        const bool okx1 = (kx1 < WW);
        v4f lp = {0,0,0,0}, ap = {0,0,0,0};

        #pragma unroll
        for (int dy = 0; dy < 13; ++dy) {
            const int row = r8 + dy;
            const half_t* p0 = &frl[(row * NPX + px0) * CF];
            const half_t* p1 = &frl[(row * NPX + px1) * CF];
            v4h blo0 = *(const v4h*)(p0 + off_lo);
            v4h bhi0 = *(const v4h*)(p0 + off_hi);
            v4h blo1 = *(const v4h*)(p1 + off_lo);
            v4h bhi1 = *(const v4h*)(p1 + off_hi);
            v4f c0 = __builtin_amdgcn_mfma_f32_16x16x16f16(alo, blo0, bias0, 0, 0, 0);
            c0     = __builtin_amdgcn_mfma_f32_16x16x16f16(ahi, bhi0, c0,    0, 0, 0);
            v4f c1 = __builtin_amdgcn_mfma_f32_16x16x16f16(alo, blo1, bias1, 0, 0, 0);
            c1     = __builtin_amdgcn_mfma_f32_16x16x16f16(ahi, bhi1, c1,    0, 0, 0);

            const int gy  = y + dy - 6;
            const int gyc = min(max(gy, 0), HH-1);
            const bool oky = (gy == gyc);
            const float* ibr = imb + (size_t)gyc * WW;
            const float iw0 = (oky && okx0) ? ibr[kx0c] : 0.f;
            const float iw1 = (oky && okx1) ? ibr[kx1c] : 0.f;

            #pragma unroll
            for (int r = 0; r < 4; ++r) {
                float e0 = __builtin_amdgcn_exp2f(c0[r]);
                float e1 = __builtin_amdgcn_exp2f(c1[r]);
                lp[r] += e0 + e1;
                ap[r] += e0 * iw0 + e1 * iw1;
            }
        }

        // reduce over the 16 key-px lanes (cols) within each row group
        #pragma unroll
        for (int r = 0; r < 4; ++r) {
            float lv = lp[r], av = ap[r];
            lv += __shfl_xor(lv, 1);  av += __shfl_xor(av, 1);
            lv += __shfl_xor(lv, 2);  av += __shfl_xor(av, 2);
            lv += __shfl_xor(lv, 4);  av += __shfl_xor(av, 4);
            lv += __shfl_xor(lv, 8);  av += __shfl_xor(av, 8);
            lp[r] = lv; ap[r] = av;
        }
        if (n < 4) {
            const float lv = n==0 ? lp[0] : n==1 ? lp[1] : n==2 ? lp[2] : lp[3];
            const float av = n==0 ? ap[0] : n==1 ? ap[1] : n==2 ? ap[2] : ap[3];
            out[(size_t)b0 * HW + (size_t)y * WW + x0 + 4*g + n] = av / lv;
        }
    }
}

extern "C" void kernel_launch(void* const* d_in, const int* in_sizes, int n_in,
                              void* d_out, int out_size, void* d_ws, size_t ws_size,
                              hipStream_t stream)
{
    const float* ft  = (const float*)d_in[0];  // feats_t  (2,32,256,256) f32
    const float* fr  = (const float*)d_in[1];  // feats_r  (2,32,256,256) f32
    const float* img = (const float*)d_in[2];  // img_r    (2,1,256,256)  f32
    float* out = (float*)d_out;                // (2,1,256,256) f32
    (void)in_sizes; (void)n_in; (void)out_size; (void)d_ws; (void)ws_size;
    corr_recon<<<256, NTHREADS, 0, stream>>>(ft, fr, img, out);
}

// Round 6
// 29.100 us; speedup vs baseline: 2.1355x; 2.1355x over previous
//
#include <hip/hip_runtime.h>
#include <stdint.h>

typedef _Float16 half_t;
typedef _Float16 v4h __attribute__((ext_vector_type(4)));
typedef float v4f __attribute__((ext_vector_type(4)));

#define HH 256
#define WW 256
#define HW (HH*WW)
#define CF 32
#define TH 8
#define TW 64
#define NROWS (TH+12)     // 20
#define NPX   (TW+16)     // 80
#define PXS   36          // f16 per px: 32 channels + 4 pad (72B stride, <=2-way bank)
#define NTHREADS 1024
#define L2E 1.44269504088896340736f

__global__ __launch_bounds__(NTHREADS, 4)
void corr_recon(const float* __restrict__ ft, const float* __restrict__ fr,
                const float* __restrict__ img, float* __restrict__ out)
{
    __shared__ half_t frl[NROWS * NPX * PXS];   // 115200 B
    __shared__ float  img_lds[NROWS * NPX];     // 6400 B

    const int bid = blockIdx.x;
    const int b0  = bid >> 7;
    const int rb  = bid & 127;
    const int y0  = (rb >> 2) * TH;    // 32 row-bands
    const int x0t = (rb & 3) * TW;     // 4 col-bands

    const int tid  = threadIdx.x;
    const int lane = tid & 63;
    const int w    = tid >> 6;         // wave 0..15
    const int n    = lane & 15;        // MFMA col lane (key px)
    const int g    = lane >> 4;        // MFMA k-group / D-row group

    const float* frb = fr  + (size_t)b0 * CF * HW;
    const float* ftb = ft  + (size_t)b0 * CF * HW;
    const float* imb = img + (size_t)b0 * HW;

    // ---- stage fr tile: f32 global -> f16 LDS (padded px stride) ----
    // partial/OOB quads go through the per-element guarded fallback (proven in R4)
    for (int i = tid; i < NROWS * 20 * 8; i += NTHREADS) {
        const int px4 = i % 20;        // 4-px group
        const int t2  = i / 20;
        const int q   = t2 & 7;        // 4-channel granule (c = 4q..4q+3)
        const int row = t2 >> 3;
        const int gy  = y0 - 6 + row;
        const int gx  = x0t - 6 + px4 * 4;
        const int gyc = min(max(gy, 0), HH-1);
        const bool oky = (gy == gyc);
        const float* src = frb + ((size_t)(4*q) * HH + gyc) * WW;
        float t[4][4];
        if (oky && gx >= 0 && gx + 3 < WW) {
            #pragma unroll
            for (int jc = 0; jc < 4; ++jc) {
                float4 v = *(const float4*)(src + (size_t)jc * HW + gx);
                t[jc][0]=v.x; t[jc][1]=v.y; t[jc][2]=v.z; t[jc][3]=v.w;
            }
        } else {
            #pragma unroll
            for (int jc = 0; jc < 4; ++jc)
                #pragma unroll
                for (int e = 0; e < 4; ++e) {
                    int x = gx + e;
                    t[jc][e] = (oky && x >= 0 && x < WW) ? src[(size_t)jc * HW + x] : 0.f;
                }
        }
        #pragma unroll
        for (int jp = 0; jp < 4; ++jp) {
            const int px = px4 * 4 + jp;
            v4h pk;
            pk[0] = (half_t)t[0][jp]; pk[1] = (half_t)t[1][jp];
            pk[2] = (half_t)t[2][jp]; pk[3] = (half_t)t[3][jp];
            *(v4h*)&frl[(row * NPX + px) * PXS + q * 4] = pk;
        }
    }
    // ---- stage img tile (zero-padded, per-element fallback for partial quads:
    //      base x0t-6 is misaligned mod 4, so edge quads straddle the border) ----
    for (int i = tid; i < NROWS * (NPX/4); i += NTHREADS) {
        const int cg = i % (NPX/4);
        const int row = i / (NPX/4);
        const int gy = y0 - 6 + row;
        const int gx = x0t - 6 + cg*4;
        const int gyc = min(max(gy, 0), HH-1);
        const bool oky = (gy == gyc);
        const float* p = imb + (size_t)gyc * WW;
        float v[4];
        if (oky && gx >= 0 && gx + 3 < WW) {
            float4 t4 = *(const float4*)(p + gx);
            v[0]=t4.x; v[1]=t4.y; v[2]=t4.z; v[3]=t4.w;
        } else {
            #pragma unroll
            for (int e = 0; e < 4; ++e) {
                int x = gx + e;
                v[e] = (oky && x >= 0 && x < WW) ? p[x] : 0.f;
            }
        }
        float4 f4; f4.x=v[0]; f4.y=v[1]; f4.z=v[2]; f4.w=v[3];
        *(float4*)&img_lds[row*NPX + cg*4] = f4;
    }

    // ---- per-lane displacement-band biases (log2 domain; exp2(-1e4)==0) ----
    v4f bias0, bias1;
    #pragma unroll
    for (int r = 0; r < 4; ++r) {
        const int m  = 4*g + r;
        const int d0 = n - m;            // tile t=0 displacement idx
        const int d1 = 16 + n - m;       // tile t=1 displacement idx
        bias0[r] = (d0 >= 0 && d0 <= 12) ? 0.f : -1e4f;
        bias1[r] = (d1 >= 0 && d1 <= 12) ? 0.f : -1e4f;
    }

    // ---- this wave's two fused jobs: q-px windows [xo0, xo0+16) and [+16, +32) ----
    const int r8  = w >> 1;            // q-row in tile
    const int xo0 = (w & 1) * 32;
    const int y   = y0 + r8;

    // A fragments (ft, pre-scaled by log2e): A[row=n][k=4g+j]
    v4h aloA, ahiA, aloB, ahiB;
    {
        const float* fa = ftb + (size_t)y * WW + (x0t + xo0 + n);
        const float* fb = fa + 16;
        #pragma unroll
        for (int j = 0; j < 4; ++j) {
            aloA[j] = (half_t)(fa[(size_t)(4*g + j)      * HW] * L2E);
            ahiA[j] = (half_t)(fa[(size_t)(16 + 4*g + j) * HW] * L2E);
            aloB[j] = (half_t)(fb[(size_t)(4*g + j)      * HW] * L2E);
            ahiB[j] = (half_t)(fb[(size_t)(16 + 4*g + j) * HW] * L2E);
        }
    }

    __syncthreads();

    const int pxb = xo0 + n;           // key-tile0 px (LDS coords)
    v4f lpA = {0,0,0,0}, apA = {0,0,0,0};
    v4f lpB = {0,0,0,0}, apB = {0,0,0,0};

    #pragma unroll 1
    for (int dy = 0; dy < 13; ++dy) {
        const int row = r8 + dy;
        const half_t* pr = &frl[(row * NPX + pxb) * PXS + 4*g];
        v4h b0lo = *(const v4h*)(pr);
        v4h b0hi = *(const v4h*)(pr + 16);
        v4h b1lo = *(const v4h*)(pr + 16*PXS);
        v4h b1hi = *(const v4h*)(pr + 16*PXS + 16);
        v4h b2lo = *(const v4h*)(pr + 32*PXS);
        v4h b2hi = *(const v4h*)(pr + 32*PXS + 16);

        v4f cA0 = __builtin_amdgcn_mfma_f32_16x16x16f16(aloA, b0lo, bias0, 0, 0, 0);
        cA0     = __builtin_amdgcn_mfma_f32_16x16x16f16(ahiA, b0hi, cA0,   0, 0, 0);
        v4f cA1 = __builtin_amdgcn_mfma_f32_16x16x16f16(aloA, b1lo, bias1, 0, 0, 0);
        cA1     = __builtin_amdgcn_mfma_f32_16x16x16f16(ahiA, b1hi, cA1,   0, 0, 0);
        v4f cB0 = __builtin_amdgcn_mfma_f32_16x16x16f16(aloB, b1lo, bias0, 0, 0, 0);
        cB0     = __builtin_amdgcn_mfma_f32_16x16x16f16(ahiB, b1hi, cB0,   0, 0, 0);
        v4f cB1 = __builtin_amdgcn_mfma_f32_16x16x16f16(aloB, b2lo, bias1, 0, 0, 0);
        cB1     = __builtin_amdgcn_mfma_f32_16x16x16f16(ahiB, b2hi, cB1,   0, 0, 0);

        const float* ir = &img_lds[row * NPX + pxb];
        const float iw0 = ir[0];
        const float iw1 = ir[16];
        const float iw2 = ir[32];

        #pragma unroll
        for (int r = 0; r < 4; ++r) {
            float eA0 = __builtin_amdgcn_exp2f(cA0[r]);
            float eA1 = __builtin_amdgcn_exp2f(cA1[r]);
            float eB0 = __builtin_amdgcn_exp2f(cB0[r]);
            float eB1 = __builtin_amdgcn_exp2f(cB1[r]);
            lpA[r] += eA0 + eA1;
            apA[r] += eA0 * iw0 + eA1 * iw1;
            lpB[r] += eB0 + eB1;
            apB[r] += eB0 * iw1 + eB1 * iw2;
        }
    }

    // ---- reduce over the 16 key-px lanes; write 2 outputs/wave-lane-group ----
    #pragma unroll
    for (int r = 0; r < 4; ++r) {
        float a0 = lpA[r], a1 = apA[r], b0v = lpB[r], b1v = apB[r];
        a0 += __shfl_xor(a0, 1);  a1 += __shfl_xor(a1, 1);
        b0v += __shfl_xor(b0v, 1); b1v += __shfl_xor(b1v, 1);
        a0 += __shfl_xor(a0, 2);  a1 += __shfl_xor(a1, 2);
        b0v += __shfl_xor(b0v, 2); b1v += __shfl_xor(b1v, 2);
        a0 += __shfl_xor(a0, 4);  a1 += __shfl_xor(a1, 4);
        b0v += __shfl_xor(b0v, 4); b1v += __shfl_xor(b1v, 4);
        a0 += __shfl_xor(a0, 8);  a1 += __shfl_xor(a1, 8);
        b0v += __shfl_xor(b0v, 8); b1v += __shfl_xor(b1v, 8);
        lpA[r] = a0; apA[r] = a1; lpB[r] = b0v; apB[r] = b1v;
    }
    if (n < 4) {
        const float lA = n==0 ? lpA[0] : n==1 ? lpA[1] : n==2 ? lpA[2] : lpA[3];
        const float aA = n==0 ? apA[0] : n==1 ? apA[1] : n==2 ? apA[2] : apA[3];
        const float lB = n==0 ? lpB[0] : n==1 ? lpB[1] : n==2 ? lpB[2] : lpB[3];
        const float aB = n==0 ? apB[0] : n==1 ? apB[1] : n==2 ? apB[2] : apB[3];
        float* orow = out + (size_t)b0 * HW + (size_t)y * WW + x0t + xo0;
        orow[4*g + n]      = aA / lA;
        orow[16 + 4*g + n] = aB / lB;
    }
}

extern "C" void kernel_launch(void* const* d_in, const int* in_sizes, int n_in,
                              void* d_out, int out_size, void* d_ws, size_t ws_size,
                              hipStream_t stream)
{
    const float* ft  = (const float*)d_in[0];  // feats_t  (2,32,256,256) f32
    const float* fr  = (const float*)d_in[1];  // feats_r  (2,32,256,256) f32
    const float* img = (const float*)d_in[2];  // img_r    (2,1,256,256)  f32
    float* out = (float*)d_out;                // (2,1,256,256) f32
    (void)in_sizes; (void)n_in; (void)out_size; (void)d_ws; (void)ws_size;
    corr_recon<<<256, NTHREADS, 0, stream>>>(ft, fr, img, out);
}

// Round 7
// 22.290 us; speedup vs baseline: 2.7879x; 1.3055x over previous
//
#include <hip/hip_runtime.h>
#include <stdint.h>

typedef _Float16 half_t;
typedef _Float16 v4h __attribute__((ext_vector_type(4)));
typedef float v4f __attribute__((ext_vector_type(4)));

#define HH 256
#define WW 256
#define HW (HH*WW)
#define CF 32
#define TH 16
#define TW 32
#define NROWS (TH+12)     // 28
#define NPX   (TW+16)     // 48
#define PXS   36          // f16 per px: 32 ch + 4 pad (72B stride; b64 reads land 4/bank = floor)
#define RSTEP (NPX*PXS)   // f16 per LDS row
#define NTHREADS 1024
#define L2E 1.44269504088896340736f

__global__ __launch_bounds__(NTHREADS, 4)
void corr_recon(const float* __restrict__ ft, const float* __restrict__ fr,
                const float* __restrict__ img, float* __restrict__ out)
{
    __shared__ half_t frl[(NROWS+1) * RSTEP];        // +1 pad row for branchless prefetch
    __shared__ float  img_lds[(NROWS+1) * NPX];

    // XCD-chunked bijective swizzle: each XCD gets a contiguous 32-block chunk
    // (a 64-row slab of one batch) so y-halo re-reads hit the local L2.
    const int bid0 = blockIdx.x;
    const int bid  = (bid0 & 7) * 32 + (bid0 >> 3);

    const int b0  = bid >> 7;
    const int rb  = bid & 127;
    const int y0  = (rb >> 3) * TH;    // 16 row-bands
    const int x0t = (rb & 7) * TW;     // 8 col-bands

    const int tid  = threadIdx.x;
    const int lane = tid & 63;
    const int w    = tid >> 6;         // wave 0..15 = query row in tile
    const int n    = lane & 15;        // MFMA col lane (key px)
    const int g    = lane >> 4;        // MFMA k-group / D-row group

    const float* frb = fr  + (size_t)b0 * CF * HW;
    const float* ftb = ft  + (size_t)b0 * CF * HW;
    const float* imb = img + (size_t)b0 * HW;

    // ---- A fragments first (global loads overlap the staging loads below) ----
    // A[m=n][k=4g+j], ft pre-scaled by log2e so softmax uses raw v_exp_f32
    const int y = y0 + w;
    v4h aloA, ahiA, aloB, ahiB;
    {
        const float* fa = ftb + (size_t)y * WW + (x0t + n);
        const float* fb = fa + 16;
        #pragma unroll
        for (int j = 0; j < 4; ++j) {
            aloA[j] = (half_t)(fa[(size_t)(4*g + j)      * HW] * L2E);
            ahiA[j] = (half_t)(fa[(size_t)(16 + 4*g + j) * HW] * L2E);
            aloB[j] = (half_t)(fb[(size_t)(4*g + j)      * HW] * L2E);
            ahiB[j] = (half_t)(fb[(size_t)(16 + 4*g + j) * HW] * L2E);
        }
    }

    // ---- stage fr tile: f32 global -> f16 LDS (padded px stride) ----
    for (int i = tid; i < NROWS * 12 * 8; i += NTHREADS) {
        const int px4 = i % 12;        // 4-px group
        const int t2  = i / 12;
        const int q   = t2 & 7;        // 4-channel granule (c = 4q..4q+3)
        const int row = t2 >> 3;
        const int gy  = y0 - 6 + row;
        const int gx  = x0t - 6 + px4 * 4;
        const int gyc = min(max(gy, 0), HH-1);
        const bool oky = (gy == gyc);
        const float* src = frb + ((size_t)(4*q) * HH + gyc) * WW;
        float t[4][4];
        if (oky && gx >= 0 && gx + 3 < WW) {
            #pragma unroll
            for (int jc = 0; jc < 4; ++jc) {
                float4 v = *(const float4*)(src + (size_t)jc * HW + gx);
                t[jc][0]=v.x; t[jc][1]=v.y; t[jc][2]=v.z; t[jc][3]=v.w;
            }
        } else {
            #pragma unroll
            for (int jc = 0; jc < 4; ++jc)
                #pragma unroll
                for (int e = 0; e < 4; ++e) {
                    int x = gx + e;
                    t[jc][e] = (oky && x >= 0 && x < WW) ? src[(size_t)jc * HW + x] : 0.f;
                }
        }
        #pragma unroll
        for (int jp = 0; jp < 4; ++jp) {
            const int px = px4 * 4 + jp;
            v4h pk;
            pk[0] = (half_t)t[0][jp]; pk[1] = (half_t)t[1][jp];
            pk[2] = (half_t)t[2][jp]; pk[3] = (half_t)t[3][jp];
            *(v4h*)&frl[(row * NPX + px) * PXS + q * 4] = pk;
        }
    }
    // ---- stage img tile (zero-padded; per-element fallback for straddling quads) ----
    for (int i = tid; i < NROWS * 12; i += NTHREADS) {
        const int px4 = i % 12;
        const int row = i / 12;
        const int gy = y0 - 6 + row;
        const int gx = x0t - 6 + px4*4;
        const int gyc = min(max(gy, 0), HH-1);
        const bool oky = (gy == gyc);
        const float* p = imb + (size_t)gyc * WW;
        float v[4];
        if (oky && gx >= 0 && gx + 3 < WW) {
            float4 t4 = *(const float4*)(p + gx);
            v[0]=t4.x; v[1]=t4.y; v[2]=t4.z; v[3]=t4.w;
        } else {
            #pragma unroll
            for (int e = 0; e < 4; ++e) {
                int x = gx + e;
                v[e] = (oky && x >= 0 && x < WW) ? p[x] : 0.f;
            }
        }
        float4 f4; f4.x=v[0]; f4.y=v[1]; f4.z=v[2]; f4.w=v[3];
        *(float4*)&img_lds[row*NPX + px4*4] = f4;
    }

    // ---- per-lane displacement-band biases (log2 domain; exp2(-1e4)==0) ----
    v4f bias0, bias1;
    #pragma unroll
    for (int r = 0; r < 4; ++r) {
        const int m  = 4*g + r;
        const int d0 = n - m;            // key-tile offset 0
        const int d1 = 16 + n - m;       // key-tile offset +16
        bias0[r] = (d0 >= 0 && d0 <= 12) ? 0.f : -1e4f;
        bias1[r] = (d1 >= 0 && d1 <= 12) ? 0.f : -1e4f;
    }

    __syncthreads();

    // ---- main loop: 1-deep software pipeline over dy ----
    const half_t* pr = &frl[(w * NPX + n) * PXS + 4*g];
    const float*  ir = &img_lds[w * NPX + n];
    v4h nb0l = *(const v4h*)(pr);
    v4h nb0h = *(const v4h*)(pr + 16);
    v4h nb1l = *(const v4h*)(pr + 16*PXS);
    v4h nb1h = *(const v4h*)(pr + 16*PXS + 16);
    v4h nb2l = *(const v4h*)(pr + 32*PXS);
    v4h nb2h = *(const v4h*)(pr + 32*PXS + 16);
    float ni0 = ir[0], ni1 = ir[16], ni2 = ir[32];

    v4f lpA = {0,0,0,0}, apA = {0,0,0,0};
    v4f lpB = {0,0,0,0}, apB = {0,0,0,0};

    #pragma unroll 1
    for (int dy = 0; dy < 13; ++dy) {
        const v4h b0l = nb0l, b0h = nb0h, b1l = nb1l,
                  b1h = nb1h, b2l = nb2l, b2h = nb2h;
        const float iw0 = ni0, iw1 = ni1, iw2 = ni2;

        // prefetch next row (dy=12 reads the pad row; values unused)
        pr += RSTEP; ir += NPX;
        nb0l = *(const v4h*)(pr);
        nb0h = *(const v4h*)(pr + 16);
        nb1l = *(const v4h*)(pr + 16*PXS);
        nb1h = *(const v4h*)(pr + 16*PXS + 16);
        nb2l = *(const v4h*)(pr + 32*PXS);
        nb2h = *(const v4h*)(pr + 32*PXS + 16);
        ni0 = ir[0]; ni1 = ir[16]; ni2 = ir[32];

        v4f cA0 = __builtin_amdgcn_mfma_f32_16x16x16f16(aloA, b0l, bias0, 0, 0, 0);
        cA0     = __builtin_amdgcn_mfma_f32_16x16x16f16(ahiA, b0h, cA0,   0, 0, 0);
        v4f cA1 = __builtin_amdgcn_mfma_f32_16x16x16f16(aloA, b1l, bias1, 0, 0, 0);
        cA1     = __builtin_amdgcn_mfma_f32_16x16x16f16(ahiA, b1h, cA1,   0, 0, 0);
        v4f cB0 = __builtin_amdgcn_mfma_f32_16x16x16f16(aloB, b1l, bias0, 0, 0, 0);
        cB0     = __builtin_amdgcn_mfma_f32_16x16x16f16(ahiB, b1h, cB0,   0, 0, 0);
        v4f cB1 = __builtin_amdgcn_mfma_f32_16x16x16f16(aloB, b2l, bias1, 0, 0, 0);
        cB1     = __builtin_amdgcn_mfma_f32_16x16x16f16(ahiB, b2h, cB1,   0, 0, 0);

        #pragma unroll
        for (int r = 0; r < 4; ++r) {
            float eA0 = __builtin_amdgcn_exp2f(cA0[r]);
            float eA1 = __builtin_amdgcn_exp2f(cA1[r]);
            float eB0 = __builtin_amdgcn_exp2f(cB0[r]);
            float eB1 = __builtin_amdgcn_exp2f(cB1[r]);
            lpA[r] += eA0 + eA1;
            apA[r] += eA0 * iw0 + eA1 * iw1;
            lpB[r] += eB0 + eB1;
            apB[r] += eB0 * iw1 + eB1 * iw2;
        }
    }

    // ---- reduce over the 16 key-px lanes; write 2×16 px per wave ----
    #pragma unroll
    for (int r = 0; r < 4; ++r) {
        float a0 = lpA[r], a1 = apA[r], b0v = lpB[r], b1v = apB[r];
        a0 += __shfl_xor(a0, 1);  a1 += __shfl_xor(a1, 1);
        b0v += __shfl_xor(b0v, 1); b1v += __shfl_xor(b1v, 1);
        a0 += __shfl_xor(a0, 2);  a1 += __shfl_xor(a1, 2);
        b0v += __shfl_xor(b0v, 2); b1v += __shfl_xor(b1v, 2);
        a0 += __shfl_xor(a0, 4);  a1 += __shfl_xor(a1, 4);
        b0v += __shfl_xor(b0v, 4); b1v += __shfl_xor(b1v, 4);
        a0 += __shfl_xor(a0, 8);  a1 += __shfl_xor(a1, 8);
        b0v += __shfl_xor(b0v, 8); b1v += __shfl_xor(b1v, 8);
        lpA[r] = a0; apA[r] = a1; lpB[r] = b0v; apB[r] = b1v;
    }
    if (n < 4) {
        const float lA = n==0 ? lpA[0] : n==1 ? lpA[1] : n==2 ? lpA[2] : lpA[3];
        const float aA = n==0 ? apA[0] : n==1 ? apA[1] : n==2 ? apA[2] : apA[3];
        const float lB = n==0 ? lpB[0] : n==1 ? lpB[1] : n==2 ? lpB[2] : lpB[3];
        const float aB = n==0 ? apB[0] : n==1 ? apB[1] : n==2 ? apB[2] : apB[3];
        float* orow = out + (size_t)b0 * HW + (size_t)y * WW + x0t;
        orow[4*g + n]      = aA / lA;
        orow[16 + 4*g + n] = aB / lB;
    }
}

extern "C" void kernel_launch(void* const* d_in, const int* in_sizes, int n_in,
                              void* d_out, int out_size, void* d_ws, size_t ws_size,
                              hipStream_t stream)
{
    const float* ft  = (const float*)d_in[0];  // feats_t  (2,32,256,256) f32
    const float* fr  = (const float*)d_in[1];  // feats_r  (2,32,256,256) f32
    const float* img = (const float*)d_in[2];  // img_r    (2,1,256,256)  f32
    float* out = (float*)d_out;                // (2,1,256,256) f32
    (void)in_sizes; (void)n_in; (void)out_size; (void)d_ws; (void)ws_size;
    corr_recon<<<256, NTHREADS, 0, stream>>>(ft, fr, img, out);
}

// Round 8
// 19.970 us; speedup vs baseline: 3.1117x; 1.1161x over previous
//
#include <hip/hip_runtime.h>
#include <stdint.h>

typedef _Float16 half_t;
typedef _Float16 v4h __attribute__((ext_vector_type(4)));
typedef float v4f __attribute__((ext_vector_type(4)));

#define HH 256
#define WW 256
#define HW (HH*WW)
#define CF 32
#define TH 16
#define TW 16
#define NROWS (TH+12)     // 28
#define NPX   (TW+16)     // 32
#define PXS   36          // f16 per px: 32 ch + 4 pad (72B stride; b64 reads 4/bank = floor)
#define RSTEP (NPX*PXS)
#define NTHREADS 1024
#define L2E 1.44269504088896340736f

__global__ __launch_bounds__(NTHREADS, 2)
void corr_recon(const float* __restrict__ ft, const float* __restrict__ fr,
                const float* __restrict__ img, float* __restrict__ out)
{
    __shared__ half_t frl[NROWS * RSTEP];        // 28*32*36*2 = 64512 B
    __shared__ float  img_lds[NROWS * NPX];      // 3584 B

    // XCD-chunked bijective swizzle: 512 blocks, chunks of 64 = one 64-row slab
    const int bid0 = blockIdx.x;
    const int bid  = (bid0 & 7) * 64 + (bid0 >> 3);

    const int b0  = bid >> 8;
    const int rb  = bid & 255;
    const int y0  = (rb >> 4) * TH;    // 16 row-bands
    const int x0t = (rb & 15) * TW;    // 16 col-bands

    const int tid  = threadIdx.x;
    const int lane = tid & 63;
    const int w    = tid >> 6;         // wave 0..15 = query row in tile
    const int n    = lane & 15;        // MFMA col lane (key px)
    const int g    = lane >> 4;        // MFMA k-group / D-row group

    const float* frb = fr  + (size_t)b0 * CF * HW;
    const float* ftb = ft  + (size_t)b0 * CF * HW;
    const float* imb = img + (size_t)b0 * HW;

    // ---- A fragments (ft pre-scaled by log2e; softmax uses raw v_exp_f32) ----
    const int y = y0 + w;
    v4h alo, ahi;
    {
        const float* fa = ftb + (size_t)y * WW + (x0t + n);
        #pragma unroll
        for (int j = 0; j < 4; ++j) {
            alo[j] = (half_t)(fa[(size_t)(4*g + j)      * HW] * L2E);
            ahi[j] = (half_t)(fa[(size_t)(16 + 4*g + j) * HW] * L2E);
        }
    }

    // ---- stage fr tile: f32 global -> f16 LDS (padded px stride) ----
    for (int i = tid; i < NROWS * 8 * 8; i += NTHREADS) {
        const int px4 = i & 7;         // 4-px group (NPX/4 = 8)
        const int q   = (i >> 3) & 7;  // 4-channel granule
        const int row = i >> 6;
        const int gy  = y0 - 6 + row;
        const int gx  = x0t - 6 + px4 * 4;
        const int gyc = min(max(gy, 0), HH-1);
        const bool oky = (gy == gyc);
        const float* src = frb + ((size_t)(4*q) * HH + gyc) * WW;
        float t[4][4];
        if (oky && gx >= 0 && gx + 3 < WW) {
            #pragma unroll
            for (int jc = 0; jc < 4; ++jc) {
                float4 v = *(const float4*)(src + (size_t)jc * HW + gx);
                t[jc][0]=v.x; t[jc][1]=v.y; t[jc][2]=v.z; t[jc][3]=v.w;
            }
        } else {
            #pragma unroll
            for (int jc = 0; jc < 4; ++jc)
                #pragma unroll
                for (int e = 0; e < 4; ++e) {
                    int x = gx + e;
                    t[jc][e] = (oky && x >= 0 && x < WW) ? src[(size_t)jc * HW + x] : 0.f;
                }
        }
        #pragma unroll
        for (int jp = 0; jp < 4; ++jp) {
            const int px = px4 * 4 + jp;
            v4h pk;
            pk[0] = (half_t)t[0][jp]; pk[1] = (half_t)t[1][jp];
            pk[2] = (half_t)t[2][jp]; pk[3] = (half_t)t[3][jp];
            *(v4h*)&frl[(row * NPX + px) * PXS + q * 4] = pk;
        }
    }
    // ---- stage img tile (zero-padded; per-element fallback for edge quads) ----
    for (int i = tid; i < NROWS * 8; i += NTHREADS) {
        const int px4 = i & 7;
        const int row = i >> 3;
        const int gy = y0 - 6 + row;
        const int gx = x0t - 6 + px4*4;
        const int gyc = min(max(gy, 0), HH-1);
        const bool oky = (gy == gyc);
        const float* p = imb + (size_t)gyc * WW;
        float v[4];
        if (oky && gx >= 0 && gx + 3 < WW) {
            float4 t4 = *(const float4*)(p + gx);
            v[0]=t4.x; v[1]=t4.y; v[2]=t4.z; v[3]=t4.w;
        } else {
            #pragma unroll
            for (int e = 0; e < 4; ++e) {
                int x = gx + e;
                v[e] = (oky && x >= 0 && x < WW) ? p[x] : 0.f;
            }
        }
        float4 f4; f4.x=v[0]; f4.y=v[1]; f4.z=v[2]; f4.w=v[3];
        *(float4*)&img_lds[row*NPX + px4*4] = f4;
    }

    // ---- per-lane displacement-band biases (log2 domain; exp2(-1e4)==0) ----
    v4f bias0, bias1;
    #pragma unroll
    for (int r = 0; r < 4; ++r) {
        const int m  = 4*g + r;
        const int d0 = n - m;            // key-tile 0
        const int d1 = 16 + n - m;       // key-tile +16
        bias0[r] = (d0 >= 0 && d0 <= 12) ? 0.f : -1e4f;
        bias1[r] = (d1 >= 0 && d1 <= 12) ? 0.f : -1e4f;
    }
    const int dm = n - 4*g;              // select: cond_r = (dm >= r)

    __syncthreads();

    v4f lp = {0,0,0,0}, ap = {0,0,0,0};

    #pragma unroll 1
    for (int dy = 0; dy < 13; ++dy) {
        const half_t* pr = &frl[((w + dy) * NPX + n) * PXS + 4*g];
        v4h b0l = *(const v4h*)(pr);
        v4h b0h = *(const v4h*)(pr + 16);
        v4h b1l = *(const v4h*)(pr + 16*PXS);
        v4h b1h = *(const v4h*)(pr + 16*PXS + 16);

        v4f c0 = __builtin_amdgcn_mfma_f32_16x16x16f16(alo, b0l, bias0, 0, 0, 0);
        c0     = __builtin_amdgcn_mfma_f32_16x16x16f16(ahi, b0h, c0,    0, 0, 0);
        v4f c1 = __builtin_amdgcn_mfma_f32_16x16x16f16(alo, b1l, bias1, 0, 0, 0);
        c1     = __builtin_amdgcn_mfma_f32_16x16x16f16(ahi, b1h, c1,    0, 0, 0);

        const float* ir = &img_lds[(w + dy) * NPX + n];
        const float iw0 = ir[0];
        const float iw1 = ir[16];

        // per (m,n) at most one of d0/d1 is in-band -> select then one exp
        #pragma unroll
        for (int r = 0; r < 4; ++r) {
            const bool cond = (dm >= r);
            float cs  = cond ? c0[r] : c1[r];
            float iws = cond ? iw0   : iw1;
            float e = __builtin_amdgcn_exp2f(cs);
            lp[r] += e;
            ap[r] += e * iws;
        }
    }

    // ---- reduce over the 16 key-px lanes; write 16 px per wave ----
    #pragma unroll
    for (int r = 0; r < 4; ++r) {
        float lv = lp[r], av = ap[r];
        lv += __shfl_xor(lv, 1);  av += __shfl_xor(av, 1);
        lv += __shfl_xor(lv, 2);  av += __shfl_xor(av, 2);
        lv += __shfl_xor(lv, 4);  av += __shfl_xor(av, 4);
        lv += __shfl_xor(lv, 8);  av += __shfl_xor(av, 8);
        lp[r] = lv; ap[r] = av;
    }
    if (n < 4) {
        const float lv = n==0 ? lp[0] : n==1 ? lp[1] : n==2 ? lp[2] : lp[3];
        const float av = n==0 ? ap[0] : n==1 ? ap[1] : n==2 ? ap[2] : ap[3];
        out[(size_t)b0 * HW + (size_t)y * WW + x0t + 4*g + n] = av / lv;
    }
}

extern "C" void kernel_launch(void* const* d_in, const int* in_sizes, int n_in,
                              void* d_out, int out_size, void* d_ws, size_t ws_size,
                              hipStream_t stream)
{
    const float* ft  = (const float*)d_in[0];  // feats_t  (2,32,256,256) f32
    const float* fr  = (const float*)d_in[1];  // feats_r  (2,32,256,256) f32
    const float* img = (const float*)d_in[2];  // img_r    (2,1,256,256)  f32
    float* out = (float*)d_out;                // (2,1,256,256) f32
    (void)in_sizes; (void)n_in; (void)out_size; (void)d_ws; (void)ws_size;
    corr_recon<<<512, NTHREADS, 0, stream>>>(ft, fr, img, out);
}

// Round 9
// 19.669 us; speedup vs baseline: 3.1594x; 1.0153x over previous
//
#include <hip/hip_runtime.h>
#include <stdint.h>

typedef _Float16 half_t;
typedef _Float16 v4h __attribute__((ext_vector_type(4)));
typedef float v4f __attribute__((ext_vector_type(4)));

#define HH 256
#define WW 256
#define HW (HH*WW)
#define CF 32
#define TH 16
#define TW 16
#define NROWS (TH+12)     // 28
#define NPX   (TW+16)     // 32
#define PXS   36          // f16 per px: 32 ch + 4 pad (72B stride; b64 reads 4/bank = floor)
#define RSTEP (NPX*PXS)
#define NTHREADS 1024
#define L2E 1.44269504088896340736f

// 8 waves/EU min -> VGPR cap 64 -> 2 blocks (32 waves) truly co-resident per CU
__global__ __launch_bounds__(NTHREADS, 8)
void corr_recon(const float* __restrict__ ft, const float* __restrict__ fr,
                const float* __restrict__ img, float* __restrict__ out)
{
    __shared__ half_t frl[NROWS * RSTEP];        // 64512 B
    __shared__ float  img_lds[NROWS * NPX];      // 3584 B  (total 68 KB; 2 blocks = 136 < 160)

    // XCD-chunked bijective swizzle: 512 blocks, chunks of 64 = one 64-row slab
    const int bid0 = blockIdx.x;
    const int bid  = (bid0 & 7) * 64 + (bid0 >> 3);

    const int b0  = bid >> 8;
    const int rb  = bid & 255;
    const int y0  = (rb >> 4) * TH;    // 16 row-bands
    const int x0t = (rb & 15) * TW;    // 16 col-bands

    const int tid  = threadIdx.x;
    const int lane = tid & 63;
    const int w    = tid >> 6;         // wave 0..15 = query row in tile
    const int n    = lane & 15;        // MFMA col lane (key px)
    const int g    = lane >> 4;        // MFMA k-group / D-row group

    const float* frb = fr  + (size_t)b0 * CF * HW;
    const float* ftb = ft  + (size_t)b0 * CF * HW;
    const float* imb = img + (size_t)b0 * HW;

    // ---- stage fr tile: f32 global -> f16 LDS (padded px stride) ----
    for (int i = tid; i < NROWS * 8 * 8; i += NTHREADS) {
        const int px4 = i & 7;         // 4-px group (NPX/4 = 8)
        const int q   = (i >> 3) & 7;  // 4-channel granule
        const int row = i >> 6;
        const int gy  = y0 - 6 + row;
        const int gx  = x0t - 6 + px4 * 4;
        const int gyc = min(max(gy, 0), HH-1);
        const bool oky = (gy == gyc);
        const float* src = frb + ((size_t)(4*q) * HH + gyc) * WW;
        float t[4][4];
        if (oky && gx >= 0 && gx + 3 < WW) {
            #pragma unroll
            for (int jc = 0; jc < 4; ++jc) {
                float4 v = *(const float4*)(src + (size_t)jc * HW + gx);
                t[jc][0]=v.x; t[jc][1]=v.y; t[jc][2]=v.z; t[jc][3]=v.w;
            }
        } else {
            #pragma unroll
            for (int jc = 0; jc < 4; ++jc)
                #pragma unroll
                for (int e = 0; e < 4; ++e) {
                    int x = gx + e;
                    t[jc][e] = (oky && x >= 0 && x < WW) ? src[(size_t)jc * HW + x] : 0.f;
                }
        }
        #pragma unroll
        for (int jp = 0; jp < 4; ++jp) {
            const int px = px4 * 4 + jp;
            v4h pk;
            pk[0] = (half_t)t[0][jp]; pk[1] = (half_t)t[1][jp];
            pk[2] = (half_t)t[2][jp]; pk[3] = (half_t)t[3][jp];
            *(v4h*)&frl[(row * NPX + px) * PXS + q * 4] = pk;
        }
    }
    // ---- stage img tile (zero-padded; per-element fallback for edge quads) ----
    for (int i = tid; i < NROWS * 8; i += NTHREADS) {
        const int px4 = i & 7;
        const int row = i >> 3;
        const int gy = y0 - 6 + row;
        const int gx = x0t - 6 + px4*4;
        const int gyc = min(max(gy, 0), HH-1);
        const bool oky = (gy == gyc);
        const float* p = imb + (size_t)gyc * WW;
        float v[4];
        if (oky && gx >= 0 && gx + 3 < WW) {
            float4 t4 = *(const float4*)(p + gx);
            v[0]=t4.x; v[1]=t4.y; v[2]=t4.z; v[3]=t4.w;
        } else {
            #pragma unroll
            for (int e = 0; e < 4; ++e) {
                int x = gx + e;
                v[e] = (oky && x >= 0 && x < WW) ? p[x] : 0.f;
            }
        }
        float4 f4; f4.x=v[0]; f4.y=v[1]; f4.z=v[2]; f4.w=v[3];
        *(float4*)&img_lds[row*NPX + px4*4] = f4;
    }

    // ---- A fragments AFTER staging (shrinks live-range overlap; VGPR<=64) ----
    const int y = y0 + w;
    v4h alo, ahi;
    {
        const float* fa = ftb + (size_t)y * WW + (x0t + n);
        #pragma unroll
        for (int j = 0; j < 4; ++j) {
            alo[j] = (half_t)(fa[(size_t)(4*g + j)      * HW] * L2E);
            ahi[j] = (half_t)(fa[(size_t)(16 + 4*g + j) * HW] * L2E);
        }
    }

    // ---- per-lane displacement-band biases (log2 domain; exp2(-1e4)==0) ----
    v4f bias0, bias1;
    #pragma unroll
    for (int r = 0; r < 4; ++r) {
        const int m  = 4*g + r;
        const int d0 = n - m;            // key-tile 0
        const int d1 = 16 + n - m;       // key-tile +16
        bias0[r] = (d0 >= 0 && d0 <= 12) ? 0.f : -1e4f;
        bias1[r] = (d1 >= 0 && d1 <= 12) ? 0.f : -1e4f;
    }
    const int dm = n - 4*g;              // select: cond_r = (dm >= r)

    __syncthreads();

    v4f lp = {0,0,0,0}, ap = {0,0,0,0};

    #pragma unroll 1
    for (int dy = 0; dy < 13; ++dy) {
        const half_t* pr = &frl[((w + dy) * NPX + n) * PXS + 4*g];
        v4h b0l = *(const v4h*)(pr);
        v4h b0h = *(const v4h*)(pr + 16);
        v4h b1l = *(const v4h*)(pr + 16*PXS);
        v4h b1h = *(const v4h*)(pr + 16*PXS + 16);

        v4f c0 = __builtin_amdgcn_mfma_f32_16x16x16f16(alo, b0l, bias0, 0, 0, 0);
        c0     = __builtin_amdgcn_mfma_f32_16x16x16f16(ahi, b0h, c0,    0, 0, 0);
        v4f c1 = __builtin_amdgcn_mfma_f32_16x16x16f16(alo, b1l, bias1, 0, 0, 0);
        c1     = __builtin_amdgcn_mfma_f32_16x16x16f16(ahi, b1h, c1,    0, 0, 0);

        const float* ir = &img_lds[(w + dy) * NPX + n];
        const float iw0 = ir[0];
        const float iw1 = ir[16];

        // per (m,n) at most one of d0/d1 is in-band -> select then one exp
        #pragma unroll
        for (int r = 0; r < 4; ++r) {
            const bool cond = (dm >= r);
            float cs  = cond ? c0[r] : c1[r];
            float iws = cond ? iw0   : iw1;
            float e = __builtin_amdgcn_exp2f(cs);
            lp[r] += e;
            ap[r] += e * iws;
        }
    }

    // ---- reduce over the 16 key-px lanes; write 16 px per wave ----
    #pragma unroll
    for (int r = 0; r < 4; ++r) {
        float lv = lp[r], av = ap[r];
        lv += __shfl_xor(lv, 1);  av += __shfl_xor(av, 1);
        lv += __shfl_xor(lv, 2);  av += __shfl_xor(av, 2);
        lv += __shfl_xor(lv, 4);  av += __shfl_xor(av, 4);
        lv += __shfl_xor(lv, 8);  av += __shfl_xor(av, 8);
        lp[r] = lv; ap[r] = av;
    }
    if (n < 4) {
        const float lv = n==0 ? lp[0] : n==1 ? lp[1] : n==2 ? lp[2] : lp[3];
        const float av = n==0 ? ap[0] : n==1 ? ap[1] : n==2 ? ap[2] : ap[3];
        out[(size_t)b0 * HW + (size_t)y * WW + x0t + 4*g + n] = av / lv;
    }
}

extern "C" void kernel_launch(void* const* d_in, const int* in_sizes, int n_in,
                              void* d_out, int out_size, void* d_ws, size_t ws_size,
                              hipStream_t stream)
{
    const float* ft  = (const float*)d_in[0];  // feats_t  (2,32,256,256) f32
    const float* fr  = (const float*)d_in[1];  // feats_r  (2,32,256,256) f32
    const float* img = (const float*)d_in[2];  // img_r    (2,1,256,256)  f32
    float* out = (float*)d_out;                // (2,1,256,256) f32
    (void)in_sizes; (void)n_in; (void)out_size; (void)d_ws; (void)ws_size;
    corr_recon<<<512, NTHREADS, 0, stream>>>(ft, fr, img, out);
}

// Round 10
// 19.006 us; speedup vs baseline: 3.2696x; 1.0349x over previous
//
#include <hip/hip_runtime.h>
#include <stdint.h>

typedef _Float16 half_t;
typedef _Float16 v4h __attribute__((ext_vector_type(4)));
typedef _Float16 v8h __attribute__((ext_vector_type(8)));
typedef float v4f __attribute__((ext_vector_type(4)));

#define HH 256
#define WW 256
#define HW (HH*WW)
#define TH 32
#define TW 16
#define NROWS (TH+12)     // 44
#define NPX   (TW+16)     // 32
#define PXS   40          // f16 per px: 32 ch (unit-reordered) + 8 pad; 80B stride, 16B units
#define NTHREADS 1024
#define L2E 1.44269504088896340736f

__global__ __launch_bounds__(NTHREADS, 4)
void corr_recon(const float* __restrict__ ft, const float* __restrict__ fr,
                const float* __restrict__ img, float* __restrict__ out)
{
    __shared__ half_t frl[NROWS * NPX * PXS];   // 112640 B
    __shared__ float  img_lds[NROWS * NPX];     // 5632 B

    // XCD-chunked bijective swizzle: 256 blocks = 8 chunks of 32
    const int bid0 = blockIdx.x;
    const int bid  = (bid0 & 7) * 32 + (bid0 >> 3);

    const int b0  = bid >> 7;
    const int rb  = bid & 127;
    const int y0  = (rb >> 4) * TH;    // 8 row-bands of 32
    const int x0t = (rb & 15) * TW;    // 16 col-bands of 16

    const int tid  = threadIdx.x;
    const int lane = tid & 63;
    const int w    = tid >> 6;         // wave 0..15 -> query rows y0+2w, y0+2w+1
    const int n    = lane & 15;        // MFMA col lane (key px slot)
    const int g    = lane >> 4;        // MFMA k-group

    const float* frb = fr  + (size_t)b0 * 32 * HW;
    const float* ftb = ft  + (size_t)b0 * 32 * HW;
    const float* imb = img + (size_t)b0 * HW;

    // ---- stage fr: granule q (ch 4q..4q+3) -> f16 offset 8*(q&3)+4*(q>>2);
    //      so the 16B unit at offset 16g holds ch {4g..4g+3, 16+4g..16+4g+3}
    //      = exactly the mfma_f32_16x16x32_f16 k-slice for lane group g.
    for (int i = tid; i < NROWS * 8 * 8; i += NTHREADS) {
        const int px4 = i & 7;         // 4-px group (NPX/4 = 8)
        const int q   = (i >> 3) & 7;  // channel granule
        const int row = i >> 6;
        const int gy  = y0 - 6 + row;
        const int gx  = x0t - 6 + px4 * 4;
        const int gyc = min(max(gy, 0), HH-1);
        const bool oky = (gy == gyc);
        const float* src = frb + ((size_t)(4*q) * HH + gyc) * WW;
        float t[4][4];
        if (oky && gx >= 0 && gx + 3 < WW) {
            #pragma unroll
            for (int jc = 0; jc < 4; ++jc) {
                float4 v = *(const float4*)(src + (size_t)jc * HW + gx);
                t[jc][0]=v.x; t[jc][1]=v.y; t[jc][2]=v.z; t[jc][3]=v.w;
            }
        } else {
            #pragma unroll
            for (int jc = 0; jc < 4; ++jc)
                #pragma unroll
                for (int e = 0; e < 4; ++e) {
                    int x = gx + e;
                    t[jc][e] = (oky && x >= 0 && x < WW) ? src[(size_t)jc * HW + x] : 0.f;
                }
        }
        const int qo = 8*(q & 3) + 4*(q >> 2);
        #pragma unroll
        for (int jp = 0; jp < 4; ++jp) {
            const int px = px4 * 4 + jp;
            v4h pk;
            pk[0] = (half_t)t[0][jp]; pk[1] = (half_t)t[1][jp];
            pk[2] = (half_t)t[2][jp]; pk[3] = (half_t)t[3][jp];
            *(v4h*)&frl[(row * NPX + px) * PXS + qo] = pk;
        }
    }
    // ---- stage img tile (zero-padded; per-element fallback for edge quads) ----
    for (int i = tid; i < NROWS * 8; i += NTHREADS) {
        const int px4 = i & 7;
        const int row = i >> 3;
        const int gy = y0 - 6 + row;
        const int gx = x0t - 6 + px4*4;
        const int gyc = min(max(gy, 0), HH-1);
        const bool oky = (gy == gyc);
        const float* p = imb + (size_t)gyc * WW;
        float v[4];
        if (oky && gx >= 0 && gx + 3 < WW) {
            float4 t4 = *(const float4*)(p + gx);
            v[0]=t4.x; v[1]=t4.y; v[2]=t4.z; v[3]=t4.w;
        } else {
            #pragma unroll
            for (int e = 0; e < 4; ++e) {
                int x = gx + e;
                v[e] = (oky && x >= 0 && x < WW) ? p[x] : 0.f;
            }
        }
        float4 f4; f4.x=v[0]; f4.y=v[1]; f4.z=v[2]; f4.w=v[3];
        *(float4*)&img_lds[row*NPX + px4*4] = f4;
    }

    // ---- A fragments: 2 query rows, ch {4g+j, 16+4g+j} pre-scaled by log2e ----
    const int y = y0 + 2*w;
    v8h a0, a1;
    {
        const float* fa = ftb + (size_t)y * WW + (x0t + n);
        #pragma unroll
        for (int j = 0; j < 4; ++j) {
            a0[j]   = (half_t)(fa[(size_t)(4*g + j)      * HW] * L2E);
            a0[4+j] = (half_t)(fa[(size_t)(16 + 4*g + j) * HW] * L2E);
            a1[j]   = (half_t)(fa[WW + (size_t)(4*g + j)      * HW] * L2E);
            a1[4+j] = (half_t)(fa[WW + (size_t)(16 + 4*g + j) * HW] * L2E);
        }
    }

    // ---- per-lane displacement-band biases (log2 domain; exp2(-1e4)==0) ----
    v4f bias0, bias1;
    #pragma unroll
    for (int r = 0; r < 4; ++r) {
        const int m  = 4*g + r;
        const int d0 = n - m;            // key-tile 0
        const int d1 = 16 + n - m;       // key-tile +16
        bias0[r] = (d0 >= 0 && d0 <= 12) ? 0.f : -1e4f;
        bias1[r] = (d1 >= 0 && d1 <= 12) ? 0.f : -1e4f;
    }
    const int dm = n - 4*g;              // select: cond_r = (dm >= r)

    __syncthreads();

    v4f lp0 = {0,0,0,0}, ap0 = {0,0,0,0};
    v4f lp1 = {0,0,0,0}, ap1 = {0,0,0,0};

    auto STEP = [&](const v8h& a, v4f& lp, v4f& ap,
                    const v8h& B0, const v8h& B1, float iw0, float iw1) {
        v4f c0 = __builtin_amdgcn_mfma_f32_16x16x32_f16(a, B0, bias0, 0, 0, 0);
        v4f c1 = __builtin_amdgcn_mfma_f32_16x16x32_f16(a, B1, bias1, 0, 0, 0);
        #pragma unroll
        for (int r = 0; r < 4; ++r) {
            const bool cond = (dm >= r);
            float cs  = cond ? c0[r] : c1[r];
            float iws = cond ? iw0   : iw1;
            float e = __builtin_amdgcn_exp2f(cs);
            lp[r] += e;
            ap[r] += e * iws;
        }
    };

    // ---- main loop: rows 2w..2w+13; row serves job0 at dy=rr, job1 at dy=rr-1.
    //      1-deep prefetch (C/N rotation); last load is row 2w+13 (<= 43). ----
    const half_t* prd = &frl[(2*w * NPX + n) * PXS + 8*g];
    const float*  ird = &img_lds[2*w * NPX + n];

    v8h C0 = *(const v8h*)(prd);
    v8h C1 = *(const v8h*)(prd + 16*PXS);
    float ci0 = ird[0], ci1 = ird[16];

    prd += NPX*PXS; ird += NPX;
    v8h N0 = *(const v8h*)(prd);
    v8h N1 = *(const v8h*)(prd + 16*PXS);
    float ni0 = ird[0], ni1 = ird[16];

    STEP(a0, lp0, ap0, C0, C1, ci0, ci1);          // rr = 0: job0 only

    #pragma unroll 1
    for (int rr = 1; rr < 13; ++rr) {
        C0 = N0; C1 = N1; ci0 = ni0; ci1 = ni1;
        prd += NPX*PXS; ird += NPX;
        N0 = *(const v8h*)(prd);
        N1 = *(const v8h*)(prd + 16*PXS);
        ni0 = ird[0]; ni1 = ird[16];
        STEP(a0, lp0, ap0, C0, C1, ci0, ci1);      // job0, dy = rr
        STEP(a1, lp1, ap1, C0, C1, ci0, ci1);      // job1, dy = rr-1
    }
    STEP(a1, lp1, ap1, N0, N1, ni0, ni1);          // rr = 13: job1 only

    // ---- reduce over the 16 key-px lanes; write 2 rows × 16 px per wave ----
    #pragma unroll
    for (int r = 0; r < 4; ++r) {
        float l0 = lp0[r], v0 = ap0[r], l1 = lp1[r], v1 = ap1[r];
        l0 += __shfl_xor(l0, 1);  v0 += __shfl_xor(v0, 1);
        l1 += __shfl_xor(l1, 1);  v1 += __shfl_xor(v1, 1);
        l0 += __shfl_xor(l0, 2);  v0 += __shfl_xor(v0, 2);
        l1 += __shfl_xor(l1, 2);  v1 += __shfl_xor(v1, 2);
        l0 += __shfl_xor(l0, 4);  v0 += __shfl_xor(v0, 4);
        l1 += __shfl_xor(l1, 4);  v1 += __shfl_xor(v1, 4);
        l0 += __shfl_xor(l0, 8);  v0 += __shfl_xor(v0, 8);
        l1 += __shfl_xor(l1, 8);  v1 += __shfl_xor(v1, 8);
        lp0[r] = l0; ap0[r] = v0; lp1[r] = l1; ap1[r] = v1;
    }
    if (n < 4) {
        const float l0 = n==0 ? lp0[0] : n==1 ? lp0[1] : n==2 ? lp0[2] : lp0[3];
        const float v0 = n==0 ? ap0[0] : n==1 ? ap0[1] : n==2 ? ap0[2] : ap0[3];
        const float l1 = n==0 ? lp1[0] : n==1 ? lp1[1] : n==2 ? lp1[2] : lp1[3];
        const float v1 = n==0 ? ap1[0] : n==1 ? ap1[1] : n==2 ? ap1[2] : ap1[3];
        float* orow = out + (size_t)b0 * HW + (size_t)y * WW + x0t + 4*g + n;
        orow[0]  = v0 / l0;
        orow[WW] = v1 / l1;
    }
}

extern "C" void kernel_launch(void* const* d_in, const int* in_sizes, int n_in,
                              void* d_out, int out_size, void* d_ws, size_t ws_size,
                              hipStream_t stream)
{
    const float* ft  = (const float*)d_in[0];  // feats_t  (2,32,256,256) f32
    const float* fr  = (const float*)d_in[1];  // feats_r  (2,32,256,256) f32
    const float* img = (const float*)d_in[2];  // img_r    (2,1,256,256)  f32
    float* out = (float*)d_out;                // (2,1,256,256) f32
    (void)in_sizes; (void)n_in; (void)out_size; (void)d_ws; (void)ws_size;
    corr_recon<<<256, NTHREADS, 0, stream>>>(ft, fr, img, out);
}